// Round 12
// baseline (337.229 us; speedup 1.0000x reference)
//
#include <hip/hip_runtime.h>
#include <hip/hip_bf16.h>

#define NN 32
#define CC 256
#define HH 56
#define WW 56
#define HP 58
#define PIX (HH * WW)          // 3136
#define MTOT (NN * PIX)        // 100352 = 392 * 256
#define BN_EPS 1e-5f

using f32x4  = __attribute__((ext_vector_type(4))) float;
using short8 = __attribute__((ext_vector_type(8))) short;

__device__ __forceinline__ void gload16(const void* g, void* l) {
    __builtin_amdgcn_global_load_lds(
        (const __attribute__((address_space(1))) void*)g,
        (__attribute__((address_space(3))) void*)l, 16, 0, 0);
}

// ---------------- layout transforms ----------------

// x NCHW fp32 -> xt padded NHWC bf16 [N][58][58][256]; borders fused (zeroed).
__global__ __launch_bounds__(256) void transform_x(const float* __restrict__ x,
                                                   __hip_bfloat16* __restrict__ xt) {
    __shared__ float t[64][65];
    const int tx = threadIdx.x & 63, ty = threadIdx.x >> 6;
    const int c0 = blockIdx.x * 64, h = blockIdx.y, n = blockIdx.z;
    const bool hIn = (h >= 1) && (h <= HH);
    if (hIn) {
        #pragma unroll
        for (int i = 0; i < 16; ++i) {
            const int c = ty + i * 4;
            float v = 0.f;
            if (tx < WW) v = x[(((size_t)n * CC + c0 + c) * HH + (h - 1)) * WW + tx];
            t[c][tx] = v;
        }
    }
    __syncthreads();
    #pragma unroll
    for (int i = 0; i < 16; ++i) {
        const int w0 = ty + i * 4;
        if (w0 < HP) {
            float v = 0.f;
            if (hIn && w0 >= 1 && w0 <= WW) v = t[tx][w0 - 1];
            xt[((n * HP + h) * HP + w0) * CC + c0 + tx] = __float2bfloat16(v);
        }
    }
}

// w [co][ci][3][3] fp32 -> wt [tap][co][ci] bf16
__global__ void transform_w(const float* __restrict__ w, __hip_bfloat16* __restrict__ wt) {
    const int co = blockIdx.x, tap = blockIdx.y, ci = threadIdx.x;
    wt[(tap * CC + co) * CC + ci] = __float2bfloat16(w[(co * CC + ci) * 9 + tap]);
}

// zero spatial border of a padded NHWC buffer (y1)
__global__ void zero_borders(__hip_bfloat16* __restrict__ buf) {
    const int i = blockIdx.x, n = blockIdx.y;
    int h, w;
    if (i < 58)       { h = 0;              w = i; }
    else if (i < 116) { h = 57;             w = i - 58; }
    else if (i < 172) { h = 1 + (i - 116);  w = 0; }
    else              { h = 1 + (i - 172);  w = 57; }
    buf[((n * HP + h) * HP + w) * CC + threadIdx.x] = __float2bfloat16(0.f);
}

// ---------------- implicit-GEMM conv3x3 + BN (+identity) + ReLU ----------------
// m201-faithful schedule: BM=256 pix x BN=256 co, BK=64, 512 thr = 8 waves
// (2M x 4N), per-wave 128x64 (acc[8][4]). LDS 128 KB dbuf.
// Per tile t, 4 phases (quadrant = (mhalf=p>>1, ks=p&1)); per phase:
//   {stage ONE half-tile || ds_read quadrant} -> barrier -> 16 MFMA -> barrier.
// Stage schedule: A0/A1(t+1) at p0/p1 (buf^1), B0/B1(t+2) at p2/p3 (buf).
// Gate: vmcnt(4) at p3 (B(t+2)'s 4 loads stay in flight) => tile t+1 fully
// landed before its p0 reads. Never drain to 0 in the main loop.
template<bool SECOND>
__global__ __launch_bounds__(512, 2) void conv_mfma(
    const __hip_bfloat16* __restrict__ act,
    const __hip_bfloat16* __restrict__ wt,
    const float* __restrict__ g, const float* __restrict__ bb,
    const float* __restrict__ rm, const float* __restrict__ rv,
    const float* __restrict__ identity,
    void* __restrict__ out)
{
    __shared__ short S[2][2][256][64];       // [buf][A=0/B=1][row][k] = 128 KB
    char* SB = (char*)S;

    const int tid  = threadIdx.x;
    const int lane = tid & 63;
    const int wid  = tid >> 6;               // 0..7
    const int wm   = wid >> 2;               // 0..1 (M)
    const int wn   = wid & 3;                // 0..3 (N)

    // T1: bijective XCD swizzle, 392 = 8 * 49.
    const int bid = blockIdx.x;
    const int mb  = (bid & 7) * 49 + (bid >> 3);   // pixel-block 0..391

    // T2: swizzled source 16B-slot (involution col16 ^= row&7; row&7 == lane>>3)
    const int scol = (lane & 7) ^ (lane >> 3);

    // Staging bases: half-tile h2, load j covers row r = h2*128 + j*64 + wid*8 + lane>>3.
    int abase[2][2], bbase[2][2];
    #pragma unroll
    for (int h2 = 0; h2 < 2; ++h2)
        #pragma unroll
        for (int j = 0; j < 2; ++j) {
            const int r = h2 * 128 + j * 64 + wid * 8 + (lane >> 3);
            const int p = mb * 256 + r;           // < 100352 (exact)
            const int n   = p / PIX;
            const int rem = p - n * PIX;
            const int h = rem / WW, w = rem - h * WW;
            abase[h2][j] = (((n * HP + h) * HP + w) * CC + scol * 8) * 2;
            bbase[h2][j] = (r * CC + scol * 8) * 2;
        }

    f32x4 acc[8][4];
    #pragma unroll
    for (int i = 0; i < 8; ++i)
        #pragma unroll
        for (int j = 0; j < 4; ++j)
            acc[i][j] = (f32x4){0.f, 0.f, 0.f, 0.f};

    const char* actB = (const char*)act;
    const char* wtB  = (const char*)wt;

    // Stage one half-tile of tile t (cic=t/9, tap=t%9): 2 gload16/thread.
    auto stageA = [&](int buf, int h2, int t) {
        const int cic = t / 9, tap = t - cic * 9;
        const int dh = tap / 3, dw = tap - dh * 3;
        const int aoff = (dh * HP + dw) * (CC * 2) + cic * 128;
        char* dst = SB + buf * 65536 + h2 * 16384 + wid * 1024;
        gload16(actB + abase[h2][0] + aoff, dst);
        gload16(actB + abase[h2][1] + aoff, dst + 8192);
    };
    auto stageB = [&](int buf, int h2, int t) {
        const int cic = t / 9, tap = t - cic * 9;
        const int boff = tap * (CC * CC * 2) + cic * 128;
        char* dst = SB + buf * 65536 + 32768 + h2 * 16384 + wid * 1024;
        gload16(wtB + bbase[h2][0] + boff, dst);
        gload16(wtB + bbase[h2][1] + boff, dst + 8192);
    };

    const int rlane = lane & 15;
    const int xorb  = (rlane & 7) << 4;      // read-side swizzle byte
    const int colb  = (lane >> 4) << 4;

    // ---- prologue: tile0 fully + B(1); gate tile0 with vmcnt(4) ----
    stageB(0, 0, 0); stageB(0, 1, 0); stageA(0, 0, 0); stageA(0, 1, 0);  // 8 loads
    stageB(1, 0, 1); stageB(1, 1, 1);                                     // 4 loads
    asm volatile("s_waitcnt vmcnt(4)" ::: "memory");  // tile 0 landed; B(1) in flight
    __builtin_amdgcn_s_barrier();
    asm volatile("" ::: "memory");

    short8 bfr[2][4];                        // B-frags ks0/ks1, held across the tile
    #pragma unroll 1
    for (int t = 0; t < 36; ++t) {
        const int cur = t & 1;
        const char* Ab = SB + cur * 65536;
        const char* Bb = SB + cur * 65536 + 32768;
        #pragma unroll
        for (int p = 0; p < 4; ++p) {
            // -- stage one half-tile (deep-pipelined schedule) --
            if (p == 0)      { if (t < 35) stageA(cur ^ 1, 0, t + 1); }
            else if (p == 1) { if (t < 35) stageA(cur ^ 1, 1, t + 1); }
            else if (p == 2) { if (t < 34) stageB(cur,     0, t + 2); }
            else             { if (t < 34) stageB(cur,     1, t + 2); }
            // -- ds_read quadrant (compiler manages lgkmcnt) --
            const int coladdr = ((p & 1) * 64 + colb) ^ xorb;
            short8 afr[4];
            #pragma unroll
            for (int mi = 0; mi < 4; ++mi)
                afr[mi] = *(const short8*)(Ab
                    + (wm * 128 + ((p >> 1) * 4 + mi) * 16 + rlane) * 128 + coladdr);
            if (p < 2) {
                #pragma unroll
                for (int nf = 0; nf < 4; ++nf)
                    bfr[p][nf] = *(const short8*)(Bb
                        + (wn * 64 + nf * 16 + rlane) * 128 + coladdr);
            }
            // -- gate for tile t+1 (once per tile, counted; tail drains) --
            if (p == 3) {
                if (t <= 33)      asm volatile("s_waitcnt vmcnt(4)" ::: "memory");
                else if (t == 34) asm volatile("s_waitcnt vmcnt(0)" ::: "memory");
            }
            asm volatile("" ::: "memory");
            __builtin_amdgcn_s_barrier();            // pre-MFMA: all reads/stages issued
            asm volatile("" ::: "memory");
            __builtin_amdgcn_s_setprio(1);
            #pragma unroll
            for (int mi = 0; mi < 4; ++mi)
                #pragma unroll
                for (int nf = 0; nf < 4; ++nf)
                    acc[(p >> 1) * 4 + mi][nf] = __builtin_amdgcn_mfma_f32_16x16x32_bf16(
                        afr[mi], bfr[p & 1][nf], acc[(p >> 1) * 4 + mi][nf], 0, 0, 0);
            __builtin_amdgcn_s_setprio(0);
            asm volatile("" ::: "memory");
            __builtin_amdgcn_s_barrier();            // phase end
            asm volatile("" ::: "memory");
        }
    }

    // ---- epilogue: BN (+identity) + ReLU ----
    const int lm = lane >> 4, ln = lane & 15;
    #pragma unroll
    for (int nf = 0; nf < 4; ++nf) {
        const int co = wn * 64 + nf * 16 + ln;
        const float scale = g[co] * rsqrtf(rv[co] + BN_EPS);
        const float bias  = bb[co] - rm[co] * scale;
        #pragma unroll
        for (int mf = 0; mf < 8; ++mf) {
            const int p0  = mb * 256 + wm * 128 + mf * 16 + lm * 4;  // %4==0
            const int n   = p0 / PIX;
            const int pr  = p0 - n * PIX;
            f32x4 v = acc[mf][nf];
            if (SECOND) {
                const size_t off = (size_t)(n * CC + co) * PIX + pr;
                const float4 id = *(const float4*)(identity + off);
                float4 o;
                o.x = fmaxf(fmaf(v[0], scale, bias) + id.x, 0.f);
                o.y = fmaxf(fmaf(v[1], scale, bias) + id.y, 0.f);
                o.z = fmaxf(fmaf(v[2], scale, bias) + id.z, 0.f);
                o.w = fmaxf(fmaf(v[3], scale, bias) + id.w, 0.f);
                *(float4*)((float*)out + off) = o;
            } else {
                const int h = pr / WW, w = pr - h * WW;   // same row (56%4==0)
                __hip_bfloat16* yp = (__hip_bfloat16*)out
                    + ((n * HP + h + 1) * HP + (w + 1)) * CC + co;
                #pragma unroll
                for (int r = 0; r < 4; ++r)
                    yp[r * CC] = __float2bfloat16(fmaxf(fmaf(v[r], scale, bias), 0.f));
            }
        }
    }
}

// ---------------- round-1 naive fallback (used only if ws too small) ----------------
__device__ __forceinline__ float rb_(float v) { return __bfloat162float(__float2bfloat16(v)); }

template<bool SECOND>
__global__ __launch_bounds__(256) void conv_bn_naive(
    const void* __restrict__ in_v, const float* __restrict__ wmat,
    const float* __restrict__ g, const float* __restrict__ b,
    const float* __restrict__ rm, const float* __restrict__ rv,
    const float* __restrict__ identity, void* __restrict__ out_v)
{
    constexpr int CI_CHUNK = 8;
    __shared__ float xs[CI_CHUNK][3][58];
    __shared__ float ws_s[4][CI_CHUNK][9];
    const int tid = threadIdx.x;
    const int co_l = tid >> 6;
    const int wl_raw = tid & 63;
    const int wl = wl_raw < (WW - 1) ? wl_raw : (WW - 1);
    const int co = blockIdx.x * 4 + co_l;
    const int h = blockIdx.y, n = blockIdx.z;
    const float* in_f = (const float*)in_v;
    const __hip_bfloat16* in_b = (const __hip_bfloat16*)in_v;
    float acc = 0.f;
    for (int ci0 = 0; ci0 < CC; ci0 += CI_CHUNK) {
        __syncthreads();
        for (int i = tid; i < CI_CHUNK * 3 * 58; i += 256) {
            int ci = i / 174, rem = i - ci * 174, r = rem / 58, col = rem - r * 58;
            int h_in = h + r - 1, x_col = col - 1;
            float v = 0.f;
            if ((unsigned)h_in < HH && (unsigned)x_col < WW) {
                int idx = ((n * CC + ci0 + ci) * HH + h_in) * WW + x_col;
                v = SECOND ? __bfloat162float(in_b[idx]) : rb_(in_f[idx]);
            }
            xs[ci][r][col] = v;
        }
        for (int i = tid; i < 4 * CI_CHUNK * 9; i += 256) {
            int c_l = i / (CI_CHUNK * 9), rem = i - c_l * (CI_CHUNK * 9);
            int ci = rem / 9, k = rem - ci * 9;
            ws_s[c_l][ci][k] = rb_(wmat[(blockIdx.x * 4 + c_l) * CC * 9 + (ci0 + ci) * 9 + k]);
        }
        __syncthreads();
        #pragma unroll
        for (int ci = 0; ci < CI_CHUNK; ++ci) {
            float wr[9];
            #pragma unroll
            for (int k = 0; k < 9; ++k) wr[k] = ws_s[co_l][ci][k];
            #pragma unroll
            for (int dh = 0; dh < 3; ++dh)
                #pragma unroll
                for (int dw = 0; dw < 3; ++dw)
                    acc += xs[ci][dh][wl + dw] * wr[dh * 3 + dw];
        }
    }
    if (wl_raw < WW) {
        float scale = g[co] * rsqrtf(rv[co] + BN_EPS);
        float bias = b[co] - rm[co] * scale;
        float v = acc * scale + bias;
        int oidx = ((n * CC + co) * HH + h) * WW + wl_raw;
        if (SECOND) {
            v += identity[oidx];
            ((float*)out_v)[oidx] = fmaxf(v, 0.f);
        } else {
            ((__hip_bfloat16*)out_v)[oidx] = __float2bfloat16(fmaxf(v, 0.f));
        }
    }
}

// ---------------- launch ----------------
extern "C" void kernel_launch(void* const* d_in, const int* in_sizes, int n_in,
                              void* d_out, int out_size, void* d_ws, size_t ws_size,
                              hipStream_t stream) {
    const float* x   = (const float*)d_in[0];
    const float* w1  = (const float*)d_in[1];
    const float* g1  = (const float*)d_in[2];
    const float* b1  = (const float*)d_in[3];
    const float* rm1 = (const float*)d_in[4];
    const float* rv1 = (const float*)d_in[5];
    const float* w2  = (const float*)d_in[6];
    const float* g2  = (const float*)d_in[7];
    const float* b2  = (const float*)d_in[8];
    const float* rm2 = (const float*)d_in[9];
    const float* rv2 = (const float*)d_in[10];

    const size_t XT_B = (size_t)NN * HP * HP * CC * 2;   // 55,115,776
    const size_t WT_B = (size_t)9 * CC * CC * 2;         // 1,179,648
    const size_t NEED = 2 * XT_B + 2 * WT_B;

    if (ws_size < NEED) {   // safety fallback: round-1 path
        __hip_bfloat16* tmp = (__hip_bfloat16*)d_ws;
        dim3 grid(CC / 4, HH, NN);
        conv_bn_naive<false><<<grid, 256, 0, stream>>>(x, w1, g1, b1, rm1, rv1, nullptr, tmp);
        conv_bn_naive<true ><<<grid, 256, 0, stream>>>(tmp, w2, g2, b2, rm2, rv2, x, d_out);
        return;
    }

    char* ws = (char*)d_ws;
    __hip_bfloat16* xt  = (__hip_bfloat16*)ws;
    __hip_bfloat16* y1  = (__hip_bfloat16*)(ws + XT_B);
    __hip_bfloat16* wt1 = (__hip_bfloat16*)(ws + 2 * XT_B);
    __hip_bfloat16* wt2 = (__hip_bfloat16*)(ws + 2 * XT_B + WT_B);

    zero_borders<<<dim3(228, NN), 256, 0, stream>>>(y1);
    transform_x <<<dim3(4, HP, NN), 256, 0, stream>>>(x, xt);   // borders fused
    transform_w <<<dim3(CC, 9), 256, 0, stream>>>(w1, wt1);
    transform_w <<<dim3(CC, 9), 256, 0, stream>>>(w2, wt2);

    conv_mfma<false><<<392, 512, 0, stream>>>(xt, wt1, g1, b1, rm1, rv1, nullptr, y1);
    conv_mfma<true ><<<392, 512, 0, stream>>>(y1, wt2, g2, b2, rm2, rv2, x, d_out);
}